// Round 1
// 486.879 us; speedup vs baseline: 1.0221x; 1.0221x over previous
//
#include <hip/hip_runtime.h>

#define N_NODES 100000
#define N_EDGES 3200000
#define D 128
#define K 8

// |score32| below this => exact fp64 repair. The bf16x3-emulated GEMM has
// score error sigma ~2e-5 (vs ~1e-5 for the pure-fp32 path), so 4e-3 is
// ~200 sigma -- same margin policy as the previous fp32 version's 2e-3.
// Flag count ~2x, repair kernels remain far off the critical path.
#define TAU 4e-3f
#define WL_CAP 262144  // repair worklist capacity

#define CHUNK 128  // nodes per head_gemm block
#define GWAVES 8   // waves per head_gemm block (512 threads, 2x4 wave tiling)

typedef float  f32x4  __attribute__((ext_vector_type(4)));
typedef __bf16 bf16x8 __attribute__((ext_vector_type(8)));

static __device__ __forceinline__ unsigned short bfbits(float f)
{
    const __bf16 b = (__bf16)f;           // RNE truncation f32 -> bf16
    return __builtin_bit_cast(unsigned short, b);
}
static __device__ __forceinline__ float bfback(unsigned short u)
{
    return (float)__builtin_bit_cast(__bf16, u);
}

// ---------------------------------------------------------------------------
// Phase 0: per-head compaction of masked node ids + per-node mask bitmap.
// ---------------------------------------------------------------------------
__global__ __launch_bounds__(256)
void compact_kernel(const float* __restrict__ mask,
                    int* __restrict__ lists,
                    int* __restrict__ cnts,
                    unsigned char* __restrict__ mb)
{
    __shared__ int wcnt[4][K];
    __shared__ int wbase[4][K];

    const int n = blockIdx.x * 256 + threadIdx.x;
    const int lane = threadIdx.x & 63;
    const int wave = threadIdx.x >> 6;
    const bool valid = (n < N_NODES);

    unsigned long long ball[K];
    int bits8 = 0;
    #pragma unroll
    for (int k = 0; k < K; ++k) {
        const bool m = valid && (mask[(size_t)n * K + k] > 0.0f);
        bits8 |= m ? (1 << k) : 0;
        ball[k] = __ballot(m);
        if (lane == 0) wcnt[wave][k] = __popcll(ball[k]);
    }
    __syncthreads();

    if (threadIdx.x < K) {
        const int k = threadIdx.x;
        const int t0 = wcnt[0][k], t1 = wcnt[1][k], t2 = wcnt[2][k], t3 = wcnt[3][k];
        const int base = (t0 + t1 + t2 + t3)
                       ? atomicAdd(&cnts[k], t0 + t1 + t2 + t3) : 0;
        wbase[0][k] = base;
        wbase[1][k] = base + t0;
        wbase[2][k] = base + t0 + t1;
        wbase[3][k] = base + t0 + t1 + t2;
    }
    __syncthreads();

    #pragma unroll
    for (int k = 0; k < K; ++k) {
        if ((ball[k] >> lane) & 1ull) {
            const int pos = __popcll(ball[k] & ((1ull << lane) - 1ull));
            lists[(size_t)k * N_NODES + wbase[wave][k] + pos] = n;
        }
    }
    if (valid) mb[n] = (unsigned char)bits8;
}

// ---------------------------------------------------------------------------
// Phase 0b: split Ww into bf16 hi/lo, TRANSPOSED to [k][col][kk] so head_gemm
// B-fragments are contiguous-in-kk 16B loads straight from L2 (64B-line exact
// across a wave: 4 lanes with the same col read one full 64B line per k-step).
// ---------------------------------------------------------------------------
__global__ __launch_bounds__(256)
void wsplit_kernel(const float* __restrict__ Ww,
                   unsigned short* __restrict__ wtH,
                   unsigned short* __restrict__ wtL)
{
    const int t = blockIdx.x * 256 + threadIdx.x;
    if (t >= K * D * D) return;
    const int k   = t >> 14;       // D*D = 16384
    const int kk  = (t >> 7) & 127;
    const int col = t & 127;
    const float v = Ww[t];
    const __bf16 h = (__bf16)v;
    const __bf16 l = (__bf16)(v - (float)h);
    const int o = (k << 14) | (col << 7) | kk;
    wtH[o] = __builtin_bit_cast(unsigned short, h);
    wtL[o] = __builtin_bit_cast(unsigned short, l);
}

// ---------------------------------------------------------------------------
// Phase 1 (bf16x3 MFMA): for each compacted (node,head):
//   t32[n,k]    = relu(x[n] @ Ww_k) . Wm_k     via x_hi@W_hi + x_hi@W_lo +
//                                                  x_lo@W_hi (fp32 MFMA acc)
//   base32[n,k] = x[n] . Wm_k                  exact fp32, folded into staging
//
// R11 (this round): the fp32 VALU path was compute-bound on the wrong pipe
// (MfmaUtil 0, VALUBusy 74%, 54% of 157 TF vector peak). bf16x3 moves the
// 13.1 real GFLOP to the 2075 TF matrix pipe (39.3 G MFMA-FLOP -> 19 us
// pipe floor vs 153 us measured fp32).
//
// Structure per block (128 nodes x 1 head, 8 waves in 2x4 tiling):
//  - stage gathered x rows as bf16 hi/lo in LDS (64 KB), XOR-swizzled
//    byte ^= (row&7)<<4 so stride-256B ds_read_b128 frags are <=2-way
//    bank-aliased (free, m136). base32 computed in fp32 on the fly here.
//  - K-loop (4 steps, no barriers): 4 B-frags global->VGPR (L2-resident Wt),
//    8 ds_read_b128 A-frags, 24 mfma_f32_16x16x32_bf16 per wave.
//    A and B frags both load 8 CONSECUTIVE k per lane at k=8*(lane>>4)+i;
//    A/B k-slot wiring is symmetric, so any consistent k-permutation
//    contracts correctly. C layout (m89-verified): col=lane&15,
//    row=(lane>>4)*4+reg -- used by the epilogue below.
//  - epilogue: relu + Wm-dot in regs, 16-lane shfl_xor reduce, cross-wave
//    LDS reduce.
// LDS 70.1 KB -> 2 blocks/CU; launch_bounds(512,4) caps VGPR at 128 for
// 4 waves/SIMD.
// ---------------------------------------------------------------------------
__global__ __launch_bounds__(512, 4)
void head_gemm_kernel(const float* __restrict__ x,
                      const unsigned short* __restrict__ wtH,
                      const unsigned short* __restrict__ wtL,
                      const float* __restrict__ Wm,
                      const int* __restrict__ lists,
                      const int* __restrict__ cnts,
                      float* __restrict__ t32,
                      float* __restrict__ base32)
{
    __shared__ __align__(16) unsigned short Ah[CHUNK * D];  // 32 KB
    __shared__ __align__(16) unsigned short Al[CHUNK * D];  // 32 KB
    __shared__ float redT[GWAVES][64];                      // 2 KB
    __shared__ float redB[CHUNK][4];                        // 2 KB
    __shared__ int   ids[CHUNK];                            // 0.5 KB

    const int bid = blockIdx.x;
    const int k = (bid >> 3) & 7;
    const int c = ((bid >> 6) << 3) | (bid & 7);   // XCD swizzle kept

    const int cnt = cnts[k];
    const int nbase = c * CHUNK;
    if (nbase >= cnt) return;            // block-uniform exit (before barriers)

    const int tid = threadIdx.x;
    const int lane = tid & 63;
    const int wave = __builtin_amdgcn_readfirstlane((int)(tid >> 6));
    const int* list = lists + (size_t)k * N_NODES;

    if (tid < CHUNK) {
        int idx = nbase + tid;
        if (idx >= cnt) idx = cnt - 1;   // tail rows duplicated, writes guarded
        ids[tid] = list[idx];
    }
    __syncthreads();

    // ---- stage A (hi/lo bf16, swizzled) + exact fp32 base partials ----
    {
        const int r = tid >> 2;          // row 0..127
        const int q = tid & 3;           // 4 threads per row
        const int id = ids[r];
        const float4* xr  = (const float4*)(x + (size_t)id * D);
        const float4* wm4 = (const float4*)(Wm + k * D);
        float bp = 0.0f;
        #pragma unroll
        for (int i = 0; i < 8; ++i) {
            const int f4 = q + 4 * i;    // 4 consecutive lanes = 64B coalesced
            const float4 v  = xr[f4];
            const float4 wv = wm4[f4];
            bp += v.x * wv.x + v.y * wv.y + v.z * wv.z + v.w * wv.w;
            ushort4 h, l;
            h.x = bfbits(v.x); l.x = bfbits(v.x - bfback(h.x));
            h.y = bfbits(v.y); l.y = bfbits(v.y - bfback(h.y));
            h.z = bfbits(v.z); l.z = bfbits(v.z - bfback(h.z));
            h.w = bfbits(v.w); l.w = bfbits(v.w - bfback(h.w));
            const int boff = ((r * 256 + f4 * 8) ^ ((r & 7) << 4)) >> 1;
            *(ushort4*)&Ah[boff] = h;
            *(ushort4*)&Al[boff] = l;
        }
        redB[r][q] = bp;
    }
    __syncthreads();

    // ---- MFMA main loop (no barriers) ----
    const int wm_ = wave >> 2;           // wave_m: rows wm_*64 .. +63
    const int wn  = wave & 3;            // wave_n: cols wn*32 .. +31
    const int l15 = lane & 15;
    const int lg  = lane >> 4;
    const int n0  = wn * 32;

    f32x4 acc[4][2];
    #pragma unroll
    for (int mf = 0; mf < 4; ++mf) {
        acc[mf][0] = (f32x4){0.f, 0.f, 0.f, 0.f};
        acc[mf][1] = (f32x4){0.f, 0.f, 0.f, 0.f};
    }

    const unsigned short* bH0 = wtH + (((k * D + n0 + l15) << 7) + 8 * lg);
    const unsigned short* bH1 = bH0 + (16 << 7);
    const unsigned short* bL0 = wtL + (((k * D + n0 + l15) << 7) + 8 * lg);
    const unsigned short* bL1 = bL0 + (16 << 7);

    #pragma unroll
    for (int s = 0; s < 4; ++s) {
        const int ko = s * 32;
        const bf16x8 Bh0 = *reinterpret_cast<const bf16x8*>(bH0 + ko);
        const bf16x8 Bh1 = *reinterpret_cast<const bf16x8*>(bH1 + ko);
        const bf16x8 Bl0 = *reinterpret_cast<const bf16x8*>(bL0 + ko);
        const bf16x8 Bl1 = *reinterpret_cast<const bf16x8*>(bL1 + ko);
        #pragma unroll
        for (int mf = 0; mf < 4; ++mf) {
            const int m = wm_ * 64 + mf * 16 + l15;
            const int byt = (m * 256 + (ko + 8 * lg) * 2) ^ ((m & 7) << 4);
            const bf16x8 Amh = *reinterpret_cast<const bf16x8*>(&Ah[byt >> 1]);
            const bf16x8 Aml = *reinterpret_cast<const bf16x8*>(&Al[byt >> 1]);
            acc[mf][0] = __builtin_amdgcn_mfma_f32_16x16x32_bf16(Amh, Bh0, acc[mf][0], 0, 0, 0);
            acc[mf][1] = __builtin_amdgcn_mfma_f32_16x16x32_bf16(Amh, Bh1, acc[mf][1], 0, 0, 0);
            acc[mf][0] = __builtin_amdgcn_mfma_f32_16x16x32_bf16(Amh, Bl0, acc[mf][0], 0, 0, 0);
            acc[mf][1] = __builtin_amdgcn_mfma_f32_16x16x32_bf16(Amh, Bl1, acc[mf][1], 0, 0, 0);
            acc[mf][0] = __builtin_amdgcn_mfma_f32_16x16x32_bf16(Aml, Bh0, acc[mf][0], 0, 0, 0);
            acc[mf][1] = __builtin_amdgcn_mfma_f32_16x16x32_bf16(Aml, Bh1, acc[mf][1], 0, 0, 0);
        }
    }

    // ---- epilogue: relu, dot with Wm over this wave's 32 cols, reduce ----
    const float wmv0 = Wm[k * D + n0 + l15];
    const float wmv1 = Wm[k * D + n0 + 16 + l15];
    float keep = 0.0f;
    #pragma unroll
    for (int mf = 0; mf < 4; ++mf) {
        #pragma unroll
        for (int r = 0; r < 4; ++r) {
            float p = fmaxf(acc[mf][0][r], 0.0f) * wmv0
                    + fmaxf(acc[mf][1][r], 0.0f) * wmv1;
            p += __shfl_xor(p, 1);
            p += __shfl_xor(p, 2);
            p += __shfl_xor(p, 4);
            p += __shfl_xor(p, 8);       // all 16 lanes of group lg hold sum
            if (l15 == mf * 4 + r) keep = p;
        }
    }
    // lane owns (mf=l15>>2, r=l15&3, g=lg) -> row_local = mf*16 + g*4 + r
    redT[wave][((l15 >> 2) << 4) + (lg << 2) + (l15 & 3)] = keep;
    __syncthreads();

    if (tid < CHUNK) {
        const int r = tid;
        const int idx = nbase + r;
        if (idx < cnt) {
            const int wg = r >> 6;       // wave_m group of this row
            const int rl = r & 63;
            const float ts = redT[wg * 4 + 0][rl] + redT[wg * 4 + 1][rl]
                           + redT[wg * 4 + 2][rl] + redT[wg * 4 + 3][rl];
            const float bs = redB[r][0] + redB[r][1] + redB[r][2] + redB[r][3];
            const int id = ids[r];
            t32[(size_t)id * K + k]    = ts;
            base32[(size_t)id * K + k] = bs;
        }
    }
}

// ---------------------------------------------------------------------------
// Phase 2 (fp32): agg32[dst,k] += t32[src,k]. Lane = (edge, head).
// ---------------------------------------------------------------------------
__global__ __launch_bounds__(256)
void scatter_kernel(const int* __restrict__ ei,
                    const unsigned char* __restrict__ mb,
                    const float* __restrict__ t32,
                    float* __restrict__ agg32)
{
    const long long tid = (long long)blockIdx.x * 256 + threadIdx.x;
    if (tid >= (long long)N_EDGES * K) return;
    const int k = (int)(tid & (K - 1));
    const long long e = tid >> 3;
    const int d = ei[(long long)N_EDGES + e];   // broadcast within 8-lane group
    const int s = ei[e];
    const unsigned md = mb[d] & mb[s];
    if (!((md >> k) & 1)) return;
    const float v = t32[(size_t)s * K + k];     // defined: src masked
    if (v != 0.0f) atomicAdd(&agg32[(size_t)d * K + k], v);
}

// ---------------------------------------------------------------------------
// Phase 3: tentative combine + flag near-zero scores for exact repair.
// ---------------------------------------------------------------------------
__global__ __launch_bounds__(256)
void combine_flag_kernel(const unsigned char* __restrict__ mb,
                         const float* __restrict__ base32,
                         const float* __restrict__ agg32,
                         float* __restrict__ out,
                         unsigned char* __restrict__ flag8,
                         double* __restrict__ s64)
{
    const int n = blockIdx.x * 256 + threadIdx.x;
    if (n >= N_NODES) return;
    const unsigned m8 = mb[n];
    float o[K];
    int cnt = 0, fl = 0;
    #pragma unroll
    for (int k = 0; k < K; ++k) {
        const float s = base32[(size_t)n * K + k] + agg32[(size_t)n * K + k];
        const bool masked = (m8 >> k) & 1;
        const bool hm = masked && (s > 0.0f);
        if (masked && fabsf(s) < TAU) fl |= (1 << k);
        o[k] = (hm && cnt < 2) ? 1.0f : 0.0f;
        cnt += hm ? 1 : 0;
    }
    float4* op = (float4*)(out + (size_t)n * K);
    op[0] = make_float4(o[0], o[1], o[2], o[3]);
    op[1] = make_float4(o[4], o[5], o[6], o[7]);
    flag8[n] = (unsigned char)fl;
    if (fl) {
        #pragma unroll
        for (int k = 0; k < K; ++k)
            if ((fl >> k) & 1) s64[(size_t)n * K + k] = 0.0;
    }
}

// ---------------------------------------------------------------------------
// Repair A: edges into flagged (dst,k) with masked src -> worklist.
// ---------------------------------------------------------------------------
__global__ __launch_bounds__(256)
void edge_flag_kernel(const int* __restrict__ ei,
                      const unsigned char* __restrict__ mb,
                      const unsigned char* __restrict__ flag8,
                      int2* __restrict__ wl,
                      int* __restrict__ wlcnt)
{
    const int e = blockIdx.x * 256 + threadIdx.x;
    if (e >= N_EDGES) return;
    const int d = ei[(long long)N_EDGES + e];
    unsigned f = flag8[d];
    if (!f) return;
    const int s = ei[e];
    f &= mb[s];
    while (f) {
        const int k = __ffs(f) - 1;
        f &= f - 1;
        const int idx = atomicAdd(wlcnt, 1);
        if (idx < WL_CAP) wl[idx] = make_int2(s | (k << 20), d);
    }
}

// ---------------------------------------------------------------------------
// Repair B: one wave per worklist entry: exact fp64 t, atomic into score64.
// ---------------------------------------------------------------------------
__global__ __launch_bounds__(256)
void repair_t_kernel(const float* __restrict__ x,
                     const float* __restrict__ Ww,
                     const float* __restrict__ Wm,
                     const int2* __restrict__ wl,
                     const int* __restrict__ wlcnt,
                     double* __restrict__ score64)
{
    const int lane = threadIdx.x & 63;
    const int waveId = blockIdx.x * 4 + (threadIdx.x >> 6);
    const int nWaves = gridDim.x * 4;
    int cnt = *wlcnt;
    if (cnt > WL_CAP) cnt = WL_CAP;
    for (int w = waveId; w < cnt; w += nWaves) {
        const int2 ent = wl[w];
        const int s = __builtin_amdgcn_readfirstlane(ent.x & 0xFFFFF);
        const int k = __builtin_amdgcn_readfirstlane(ent.x >> 20);
        const int d = ent.y;
        const float* xr = x + (size_t)s * D;
        const float* Wk = Ww + (size_t)k * D * D;
        double c0 = 0.0, c1 = 0.0;
        for (int j = 0; j < D; ++j) {
            const double xd = (double)xr[j];
            c0 = fma(xd, (double)Wk[j * D + lane], c0);
            c1 = fma(xd, (double)Wk[j * D + lane + 64], c1);
        }
        double ts = fmax(c0, 0.0) * (double)Wm[k * D + lane]
                  + fmax(c1, 0.0) * (double)Wm[k * D + lane + 64];
        #pragma unroll
        for (int off = 32; off > 0; off >>= 1) ts += __shfl_xor(ts, off);
        if (lane == 0) atomicAdd(&score64[(size_t)d * K + k], ts);
    }
}

// ---------------------------------------------------------------------------
// Repair C: rewrite output rows of flagged nodes using exact scores.
// ---------------------------------------------------------------------------
__global__ __launch_bounds__(256)
void repair_combine_kernel(const float* __restrict__ x,
                           const unsigned char* __restrict__ mb,
                           const float* __restrict__ Wm,
                           const float* __restrict__ base32,
                           const float* __restrict__ agg32,
                           const double* __restrict__ score64,
                           const unsigned char* __restrict__ flag8,
                           float* __restrict__ out)
{
    const int n = blockIdx.x * 256 + threadIdx.x;
    if (n >= N_NODES) return;
    const unsigned f = flag8[n];
    if (!f) return;
    const unsigned m8 = mb[n];
    float o[K];
    int cnt = 0;
    #pragma unroll
    for (int k = 0; k < K; ++k) {
        bool hm;
        if ((f >> k) & 1) {
            double b = 0.0;
            for (int j = 0; j < D; ++j)
                b = fma((double)x[(size_t)n * D + j], (double)Wm[k * D + j], b);
            hm = (b + score64[(size_t)n * K + k]) > 0.0;
        } else {
            hm = ((m8 >> k) & 1) &&
                 ((base32[(size_t)n * K + k] + agg32[(size_t)n * K + k]) > 0.0f);
        }
        o[k] = (hm && cnt < 2) ? 1.0f : 0.0f;
        cnt += hm ? 1 : 0;
    }
    float4* op = (float4*)(out + (size_t)n * K);
    op[0] = make_float4(o[0], o[1], o[2], o[3]);
    op[1] = make_float4(o[4], o[5], o[6], o[7]);
}

extern "C" void kernel_launch(void* const* d_in, const int* in_sizes, int n_in,
                              void* d_out, int out_size, void* d_ws, size_t ws_size,
                              hipStream_t stream)
{
    const float* x    = (const float*)d_in[0];
    const int*   ei   = (const int*)d_in[1];   // edge_index [2, E] int32
    const float* mask = (const float*)d_in[2]; // [N, K]
    const float* Ww   = (const float*)d_in[3]; // [K, D, D]
    const float* Wm   = (const float*)d_in[4]; // [K, D, 1]
    float* out = (float*)d_out;                // [N, K] float32

    // workspace layout:
    //   [0, 3.2M)            t32      f32[N*K]   (gated reads, no memset)
    //   [3.2M, 6.4M)         agg32    f32[N*K]
    //   [6.4M, 12.8M)        s64      f64[N*K]  (live only from combine_flag on)
    //     overlay [6.4M, 9.6M)    lists  int[K][N]          (dead after head_gemm)
    //     overlay [9.6M, 10.13M)  wtH/wtL bf16[K][D][D] x2  (dead after head_gemm)
    //   [12.8M, +100000)     flag8    u8[N]
    //   [12,900,000, +32)    cnts     int[8]
    //   [12,900,032, +4+pad) wlcnt    int
    //   [12,900,040, +2M)    wl       int2[WL_CAP]
    //   [14,997,192, +3.2M)  base32   f32[N*K]
    //   [18,197,192, +100000) mb      u8[N]      (end ~18.3 MB, unchanged)
    char* w = (char*)d_ws;
    float*          t32    = (float*)w;
    float*          agg32  = (float*)(w + 3200000);
    double*         s64    = (double*)(w + 6400000);
    int*            lists  = (int*)(w + 6400000);
    unsigned short* wtH    = (unsigned short*)(w + 9600000);
    unsigned short* wtL    = (unsigned short*)(w + 9600000 + 262144);
    unsigned char*  flag8  = (unsigned char*)(w + 12800000);
    int*            cnts   = (int*)(w + 12900000);
    int*            wlcnt  = (int*)(w + 12900032);
    int2*           wl     = (int2*)(w + 12900040);
    float*          b32    = (float*)(w + 12900040 + (size_t)WL_CAP * 8);
    unsigned char*  mb     = (unsigned char*)(w + 12900040 + (size_t)WL_CAP * 8 + 3200000);

    hipMemsetAsync(agg32, 0, 3200000, stream);
    hipMemsetAsync(w + 12900000, 0, 64, stream);

    wsplit_kernel<<<(K * D * D + 255) / 256, 256, 0, stream>>>(Ww, wtH, wtL);

    compact_kernel<<<(N_NODES + 255) / 256, 256, 0, stream>>>(mask, lists, cnts, mb);

    const int nchunks = (N_NODES + CHUNK - 1) / CHUNK;           // 782
    const int nc8 = (nchunks + 7) & ~7;                           // 784
    head_gemm_kernel<<<nc8 * K, 512, 0, stream>>>(x, wtH, wtL, Wm, lists, cnts, t32, b32);

    const long long nek = (long long)N_EDGES * K;
    scatter_kernel<<<(int)((nek + 255) / 256), 256, 0, stream>>>(ei, mb, t32, agg32);

    combine_flag_kernel<<<(N_NODES + 255) / 256, 256, 0, stream>>>(
        mb, b32, agg32, out, flag8, s64);

    edge_flag_kernel<<<(N_EDGES + 255) / 256, 256, 0, stream>>>(
        ei, mb, flag8, wl, wlcnt);

    repair_t_kernel<<<512, 256, 0, stream>>>(x, Ww, Wm, wl, wlcnt, s64);

    repair_combine_kernel<<<(N_NODES + 255) / 256, 256, 0, stream>>>(
        x, mb, Wm, b32, agg32, s64, flag8, out);
}